// Round 1
// baseline (1314.542 us; speedup 1.0000x reference)
//
#include <hip/hip_runtime.h>
#include <math.h>

constexpr int NB = 64;
constexpr int NS = 1024;
constexpr int NH = 1024;
constexpr int NE = 1024;
constexpr int NV = 50257;
constexpr int NK2 = 2048;

// ---------------- gates GEMM: gates[b][j] = sum_k [xe|h][b][k] * [Wih|Whh][j][k] + bih[j]+bhh[j]
__global__ __launch_bounds__(256) void k_gates(const int* __restrict__ x,
    const float* __restrict__ h, const float* __restrict__ emb,
    const float* __restrict__ Wih, const float* __restrict__ bih,
    const float* __restrict__ Whh, const float* __restrict__ bhh,
    float* __restrict__ gates) {
  __shared__ float As[64][33];
  __shared__ float Ws[32][33];
  int tid = threadIdx.x;
  int j0 = blockIdx.x * 32;
  int tx = tid & 7, ty = tid >> 3;
  float acc[2][4] = {};
  for (int k0 = 0; k0 < 2048; k0 += 32) {
#pragma unroll
    for (int p = 0; p < 8; ++p) {
      int l = tid + p * 256;
      int bb = l >> 5, kk = l & 31;
      int k = k0 + kk;
      float v;
      if (k < NE) v = emb[(long)x[bb] * NE + k];
      else        v = h[bb * NH + (k - NE)];
      As[bb][kk] = v;
    }
#pragma unroll
    for (int p = 0; p < 4; ++p) {
      int l = tid + p * 256;
      int jj = l >> 5, kk = l & 31;
      int k = k0 + kk;
      int j = j0 + jj;
      float v;
      if (k < NE) v = Wih[j * NE + k];
      else        v = Whh[j * NH + (k - NE)];
      Ws[jj][kk] = v;
    }
    __syncthreads();
#pragma unroll
    for (int kk = 0; kk < 32; ++kk) {
      float a0 = As[ty * 2 + 0][kk], a1 = As[ty * 2 + 1][kk];
#pragma unroll
      for (int ji = 0; ji < 4; ++ji) {
        float w = Ws[tx * 4 + ji][kk];
        acc[0][ji] += a0 * w;
        acc[1][ji] += a1 * w;
      }
    }
    __syncthreads();
  }
#pragma unroll
  for (int bi = 0; bi < 2; ++bi)
#pragma unroll
    for (int ji = 0; ji < 4; ++ji) {
      int b = ty * 2 + bi, j = j0 + tx * 4 + ji;
      gates[b * 4096 + j] = acc[bi][ji] + bih[j] + bhh[j];
    }
}

// ---------------- LSTM cell elementwise
__global__ __launch_bounds__(256) void k_lstm(const float* __restrict__ gates,
    const float* __restrict__ c, float* __restrict__ hc_out) {
  int t = blockIdx.x * 256 + threadIdx.x;  // 0..NB*NH
  int b = t >> 10, hh = t & 1023;
  float ig = gates[b * 4096 + hh];
  float fg = gates[b * 4096 + 1024 + hh];
  float gg = gates[b * 4096 + 2048 + hh];
  float og = gates[b * 4096 + 3072 + hh];
  float i_ = 1.f / (1.f + expf(-ig));
  float f_ = 1.f / (1.f + expf(-fg));
  float g_ = tanhf(gg);
  float o_ = 1.f / (1.f + expf(-og));
  float cn = f_ * c[t] + i_ * g_;
  float hn = o_ * tanhf(cn);
  hc_out[t] = hn;                 // h_new
  hc_out[NB * NH + t] = cn;       // c_new
}

// ---------------- t = h_new @ W_bilin  (t[b][k] = sum_h hn[b][h]*Wb[h][k])
__global__ __launch_bounds__(256) void k_bilin(const float* __restrict__ hnew,
    const float* __restrict__ Wb, float* __restrict__ t_out) {
  int b = blockIdx.x >> 2;
  int k = ((blockIdx.x & 3) << 8) + threadIdx.x;
  const float* hb = hnew + b * NH;
  float acc = 0.f;
#pragma unroll 8
  for (int hh = 0; hh < NH; ++hh)
    acc += hb[hh] * Wb[hh * NH + k];
  t_out[b * NH + k] = acc;
}

// ---------------- energy[b][s] = dot(t[b], enc[b][s])   one wave per (b,s)
__global__ __launch_bounds__(256) void k_energy(const float* __restrict__ t_in,
    const float* __restrict__ enc, float* __restrict__ energy) {
  int blk = blockIdx.x;              // NB*NS/4 blocks
  int b = blk >> 8;
  int s = ((blk & 255) << 2) + (threadIdx.x >> 6);
  int lane = threadIdx.x & 63;
  const float4* tp = (const float4*)(t_in + b * NH);
  const float4* ep = (const float4*)(enc + ((size_t)b * NS + s) * NH);
  float acc = 0.f;
#pragma unroll
  for (int rep = 0; rep < 4; ++rep) {
    float4 a = tp[rep * 64 + lane];
    float4 e = ep[rep * 64 + lane];
    acc += a.x * e.x + a.y * e.y + a.z * e.z + a.w * e.w;
  }
#pragma unroll
  for (int off = 32; off; off >>= 1)
    acc += __shfl_xor(acc, off);
  if (lane == 0) energy[b * NS + s] = acc;
}

// ---------------- softmax(energy * mask) over full S (masked entries = 0, INCLUDED)
__global__ __launch_bounds__(256) void k_softmax(const float* __restrict__ energy,
    const int* __restrict__ length, float* __restrict__ attn) {
  __shared__ float red[256];
  int b = blockIdx.x, tid = threadIdx.x;
  int len = length[b];
  float vals[4];
  float m = -1e30f;
#pragma unroll
  for (int p = 0; p < 4; ++p) {
    int s = tid + p * 256;
    float v = (s < len) ? energy[b * NS + s] : 0.f;
    vals[p] = v;
    m = fmaxf(m, v);
  }
  red[tid] = m; __syncthreads();
  for (int o = 128; o; o >>= 1) { if (tid < o) red[tid] = fmaxf(red[tid], red[tid + o]); __syncthreads(); }
  m = red[0]; __syncthreads();
  float sum = 0.f;
#pragma unroll
  for (int p = 0; p < 4; ++p) { vals[p] = expf(vals[p] - m); sum += vals[p]; }
  red[tid] = sum; __syncthreads();
  for (int o = 128; o; o >>= 1) { if (tid < o) red[tid] += red[tid + o]; __syncthreads(); }
  float inv = 1.f / red[0];
#pragma unroll
  for (int p = 0; p < 4; ++p) attn[b * NS + tid + p * 256] = vals[p] * inv;
}

// ---------------- context partials over s-chunks
__global__ __launch_bounds__(256) void k_ctx_partial(const float* __restrict__ attn,
    const float* __restrict__ enc, float* __restrict__ partial) {
  int blk = blockIdx.x;      // NB*4*8
  int b = blk >> 5;
  int hc = (blk >> 3) & 3;
  int sc = blk & 7;
  int h = (hc << 8) + threadIdx.x;
  float acc = 0.f;
  int s0 = sc * 128;
  for (int s = s0; s < s0 + 128; ++s)
    acc += attn[b * NS + s] * enc[((size_t)b * NS + s) * NH + h];
  partial[((sc * NB + b) << 10) + h] = acc;
}

__global__ __launch_bounds__(256) void k_ctx_reduce(const float* __restrict__ partial,
    float* __restrict__ context) {
  int t = blockIdx.x * 256 + threadIdx.x;  // NB*NH
  float acc = 0.f;
#pragma unroll
  for (int sc = 0; sc < 8; ++sc) acc += partial[((sc * NB) << 10) + t];
  context[t] = acc;
}

// ---------------- out[b][v] = dot([context|h_new][b], W_out[v]) + b_out[v]
__global__ __launch_bounds__(256) void k_out(const float* __restrict__ context,
    const float* __restrict__ hnew, const float* __restrict__ Wout,
    const float* __restrict__ bout, float* __restrict__ out) {
  __shared__ float As[64][33];
  __shared__ float Ws[64][33];
  int tid = threadIdx.x;
  int v0 = blockIdx.x * 64;
  int tx = tid & 15, ty = tid >> 4;
  float acc[4][4] = {};
  for (int k0 = 0; k0 < NK2; k0 += 32) {
#pragma unroll
    for (int p = 0; p < 8; ++p) {
      int l = tid + p * 256;
      int bb = l >> 5, kk = l & 31;
      int k = k0 + kk;
      As[bb][kk] = (k < NH) ? context[bb * NH + k] : hnew[bb * NH + k - NH];
    }
#pragma unroll
    for (int p = 0; p < 8; ++p) {
      int l = tid + p * 256;
      int vv = l >> 5, kk = l & 31;
      int v = v0 + vv;
      Ws[vv][kk] = (v < NV) ? Wout[(size_t)v * NK2 + k0 + kk] : 0.f;
    }
    __syncthreads();
#pragma unroll
    for (int kk = 0; kk < 32; ++kk) {
      float a[4], w[4];
#pragma unroll
      for (int bi = 0; bi < 4; ++bi) a[bi] = As[ty * 4 + bi][kk];
#pragma unroll
      for (int ji = 0; ji < 4; ++ji) w[ji] = Ws[tx * 4 + ji][kk];
#pragma unroll
      for (int bi = 0; bi < 4; ++bi)
#pragma unroll
        for (int ji = 0; ji < 4; ++ji)
          acc[bi][ji] += a[bi] * w[ji];
    }
    __syncthreads();
  }
#pragma unroll
  for (int bi = 0; bi < 4; ++bi)
#pragma unroll
    for (int ji = 0; ji < 4; ++ji) {
      int b = ty * 4 + bi, v = v0 + tx * 4 + ji;
      if (v < NV) out[(size_t)b * NV + v] = acc[bi][ji] + bout[v];
    }
}

extern "C" void kernel_launch(void* const* d_in, const int* in_sizes, int n_in,
                              void* d_out, int out_size, void* d_ws, size_t ws_size,
                              hipStream_t stream) {
  const int*   x      = (const int*)d_in[0];
  const float* h      = (const float*)d_in[1];
  const float* c      = (const float*)d_in[2];
  const float* enc    = (const float*)d_in[3];
  const int*   length = (const int*)d_in[4];
  const float* emb    = (const float*)d_in[5];
  const float* Wih    = (const float*)d_in[6];
  const float* bih    = (const float*)d_in[7];
  const float* Whh    = (const float*)d_in[8];
  const float* bhh    = (const float*)d_in[9];
  const float* Wb     = (const float*)d_in[10];
  const float* Wout   = (const float*)d_in[11];
  const float* bout   = (const float*)d_in[12];

  float* out = (float*)d_out;
  float* hn  = out + (size_t)NB * NV;          // h_new region of d_out
  // c_new region = hn + NB*NH (written by k_lstm)

  float* ws      = (float*)d_ws;
  float* gates   = ws;                              // NB*4H
  float* t_ws    = gates + NB * 4 * NH;             // NB*NH
  float* energy  = t_ws + NB * NH;                  // NB*NS
  float* attn    = energy + NB * NS;                // NB*NS
  float* partial = attn + NB * NS;                  // 8*NB*NH
  float* context = partial + 8 * NB * NH;           // NB*NH

  k_gates<<<4096 / 32, 256, 0, stream>>>(x, h, emb, Wih, bih, Whh, bhh, gates);
  k_lstm<<<NB * NH / 256, 256, 0, stream>>>(gates, c, hn);
  k_bilin<<<NB * 4, 256, 0, stream>>>(hn, Wb, t_ws);
  k_energy<<<NB * NS / 4, 256, 0, stream>>>(t_ws, enc, energy);
  k_softmax<<<NB, 256, 0, stream>>>(energy, length, attn);
  k_ctx_partial<<<NB * 4 * 8, 256, 0, stream>>>(attn, enc, partial);
  k_ctx_reduce<<<NB * NH / 256, 256, 0, stream>>>(partial, context);
  k_out<<<(NV + 63) / 64, 256, 0, stream>>>(context, hn, Wout, bout, out);
}

// Round 2
// 742.641 us; speedup vs baseline: 1.7701x; 1.7701x over previous
//
#include <hip/hip_runtime.h>
#include <math.h>

constexpr int NB = 64;
constexpr int NS = 1024;
constexpr int NH = 1024;
constexpr int NE = 1024;
constexpr int NV = 50257;
constexpr int NK2 = 2048;

typedef __bf16 bf16_8 __attribute__((ext_vector_type(8)));
typedef float  f32x4  __attribute__((ext_vector_type(4)));

// ---------------- gates GEMM: gates[b][j] = sum_k [xe|h][b][k] * [Wih|Whh][j][k] + bih[j]+bhh[j]
__global__ __launch_bounds__(256) void k_gates(const int* __restrict__ x,
    const float* __restrict__ h, const float* __restrict__ emb,
    const float* __restrict__ Wih, const float* __restrict__ bih,
    const float* __restrict__ Whh, const float* __restrict__ bhh,
    float* __restrict__ gates) {
  __shared__ float As[64][33];
  __shared__ float Ws[32][33];
  int tid = threadIdx.x;
  int j0 = blockIdx.x * 32;
  int tx = tid & 7, ty = tid >> 3;
  float acc[2][4] = {};
  for (int k0 = 0; k0 < 2048; k0 += 32) {
#pragma unroll
    for (int p = 0; p < 8; ++p) {
      int l = tid + p * 256;
      int bb = l >> 5, kk = l & 31;
      int k = k0 + kk;
      float v;
      if (k < NE) v = emb[(long)x[bb] * NE + k];
      else        v = h[bb * NH + (k - NE)];
      As[bb][kk] = v;
    }
#pragma unroll
    for (int p = 0; p < 4; ++p) {
      int l = tid + p * 256;
      int jj = l >> 5, kk = l & 31;
      int k = k0 + kk;
      int j = j0 + jj;
      float v;
      if (k < NE) v = Wih[j * NE + k];
      else        v = Whh[j * NH + (k - NE)];
      Ws[jj][kk] = v;
    }
    __syncthreads();
#pragma unroll
    for (int kk = 0; kk < 32; ++kk) {
      float a0 = As[ty * 2 + 0][kk], a1 = As[ty * 2 + 1][kk];
#pragma unroll
      for (int ji = 0; ji < 4; ++ji) {
        float w = Ws[tx * 4 + ji][kk];
        acc[0][ji] += a0 * w;
        acc[1][ji] += a1 * w;
      }
    }
    __syncthreads();
  }
#pragma unroll
  for (int bi = 0; bi < 2; ++bi)
#pragma unroll
    for (int ji = 0; ji < 4; ++ji) {
      int b = ty * 2 + bi, j = j0 + tx * 4 + ji;
      gates[b * 4096 + j] = acc[bi][ji] + bih[j] + bhh[j];
    }
}

// ---------------- LSTM cell elementwise
__global__ __launch_bounds__(256) void k_lstm(const float* __restrict__ gates,
    const float* __restrict__ c, float* __restrict__ hc_out) {
  int t = blockIdx.x * 256 + threadIdx.x;  // 0..NB*NH
  int b = t >> 10, hh = t & 1023;
  float ig = gates[b * 4096 + hh];
  float fg = gates[b * 4096 + 1024 + hh];
  float gg = gates[b * 4096 + 2048 + hh];
  float og = gates[b * 4096 + 3072 + hh];
  float i_ = 1.f / (1.f + expf(-ig));
  float f_ = 1.f / (1.f + expf(-fg));
  float g_ = tanhf(gg);
  float o_ = 1.f / (1.f + expf(-og));
  float cn = f_ * c[t] + i_ * g_;
  float hn = o_ * tanhf(cn);
  hc_out[t] = hn;                 // h_new
  hc_out[NB * NH + t] = cn;       // c_new
}

// ---------------- t = h_new @ W_bilin  (t[b][k] = sum_h hn[b][h]*Wb[h][k])
__global__ __launch_bounds__(256) void k_bilin(const float* __restrict__ hnew,
    const float* __restrict__ Wb, float* __restrict__ t_out) {
  int b = blockIdx.x >> 2;
  int k = ((blockIdx.x & 3) << 8) + threadIdx.x;
  const float* hb = hnew + b * NH;
  float acc = 0.f;
#pragma unroll 8
  for (int hh = 0; hh < NH; ++hh)
    acc += hb[hh] * Wb[hh * NH + k];
  t_out[b * NH + k] = acc;
}

// ---------------- energy[b][s] = dot(t[b], enc[b][s])   one wave per (b,s)
__global__ __launch_bounds__(256) void k_energy(const float* __restrict__ t_in,
    const float* __restrict__ enc, float* __restrict__ energy) {
  int blk = blockIdx.x;              // NB*NS/4 blocks
  int b = blk >> 8;
  int s = ((blk & 255) << 2) + (threadIdx.x >> 6);
  int lane = threadIdx.x & 63;
  const float4* tp = (const float4*)(t_in + b * NH);
  const float4* ep = (const float4*)(enc + ((size_t)b * NS + s) * NH);
  float acc = 0.f;
#pragma unroll
  for (int rep = 0; rep < 4; ++rep) {
    float4 a = tp[rep * 64 + lane];
    float4 e = ep[rep * 64 + lane];
    acc += a.x * e.x + a.y * e.y + a.z * e.z + a.w * e.w;
  }
#pragma unroll
  for (int off = 32; off; off >>= 1)
    acc += __shfl_xor(acc, off);
  if (lane == 0) energy[b * NS + s] = acc;
}

// ---------------- softmax(energy * mask) over full S (masked entries = 0, INCLUDED)
__global__ __launch_bounds__(256) void k_softmax(const float* __restrict__ energy,
    const int* __restrict__ length, float* __restrict__ attn) {
  __shared__ float red[256];
  int b = blockIdx.x, tid = threadIdx.x;
  int len = length[b];
  float vals[4];
  float m = -1e30f;
#pragma unroll
  for (int p = 0; p < 4; ++p) {
    int s = tid + p * 256;
    float v = (s < len) ? energy[b * NS + s] : 0.f;
    vals[p] = v;
    m = fmaxf(m, v);
  }
  red[tid] = m; __syncthreads();
  for (int o = 128; o; o >>= 1) { if (tid < o) red[tid] = fmaxf(red[tid], red[tid + o]); __syncthreads(); }
  m = red[0]; __syncthreads();
  float sum = 0.f;
#pragma unroll
  for (int p = 0; p < 4; ++p) { vals[p] = expf(vals[p] - m); sum += vals[p]; }
  red[tid] = sum; __syncthreads();
  for (int o = 128; o; o >>= 1) { if (tid < o) red[tid] += red[tid + o]; __syncthreads(); }
  float inv = 1.f / red[0];
#pragma unroll
  for (int p = 0; p < 4; ++p) attn[b * NS + tid + p * 256] = vals[p] * inv;
}

// ---------------- context partials over s-chunks
__global__ __launch_bounds__(256) void k_ctx_partial(const float* __restrict__ attn,
    const float* __restrict__ enc, float* __restrict__ partial) {
  int blk = blockIdx.x;      // NB*4*8
  int b = blk >> 5;
  int hc = (blk >> 3) & 3;
  int sc = blk & 7;
  int h = (hc << 8) + threadIdx.x;
  float acc = 0.f;
  int s0 = sc * 128;
  for (int s = s0; s < s0 + 128; ++s)
    acc += attn[b * NS + s] * enc[((size_t)b * NS + s) * NH + h];
  partial[((sc * NB + b) << 10) + h] = acc;
}

__global__ __launch_bounds__(256) void k_ctx_reduce(const float* __restrict__ partial,
    float* __restrict__ context) {
  int t = blockIdx.x * 256 + threadIdx.x;  // NB*NH
  float acc = 0.f;
#pragma unroll
  for (int sc = 0; sc < 8; ++sc) acc += partial[((sc * NB) << 10) + t];
  context[t] = acc;
}

// ---------------- convert A = [context | h_new] (64 x 2048) to bf16
__global__ __launch_bounds__(256) void k_cvtA(const float* __restrict__ ctx,
    const float* __restrict__ hn, __bf16* __restrict__ A) {
  int t = blockIdx.x * 256 + threadIdx.x;  // 0..131071
  int b = t >> 11, k = t & 2047;
  float v = (k < NH) ? ctx[b * NH + k] : hn[b * NH + (k - NH)];
  A[t] = (__bf16)v;
}

// ---------------- out[b][v] = dot(A[b], W_out[v]) + b_out[v]  via bf16 MFMA
// One wave = 16 v-columns x full K; 4 waves/block (no LDS, no barriers).
// W_out streamed global->reg->cvt->MFMA (zero reuse). A bf16, L1/L2 resident.
__global__ __launch_bounds__(256) void k_out_mfma(const __bf16* __restrict__ A,
    const float* __restrict__ Wout, const float* __restrict__ bout,
    float* __restrict__ out) {
  int lane = threadIdx.x & 63;
  int wave = threadIdx.x >> 6;
  int col  = lane & 15;          // N index within tile / M-row index for A frags
  int grp  = lane >> 4;          // 0..3 (k-group)
  int v0   = blockIdx.x * 64 + wave * 16;
  int vrow = v0 + col;
  int vcl  = vrow < NV ? vrow : NV - 1;

  const float*  wp = Wout + (size_t)vcl * NK2 + grp * 8;
  const __bf16* ap = A + col * NK2 + grp * 8;

  f32x4 acc0 = {0.f, 0.f, 0.f, 0.f};
  f32x4 acc1 = {0.f, 0.f, 0.f, 0.f};
  f32x4 acc2 = {0.f, 0.f, 0.f, 0.f};
  f32x4 acc3 = {0.f, 0.f, 0.f, 0.f};

#pragma unroll 4
  for (int ks = 0; ks < 64; ++ks) {
    int kb = ks * 32;
    float4 b0 = *(const float4*)(wp + kb);
    float4 b1 = *(const float4*)(wp + kb + 4);
    bf16_8 bf;
    bf[0] = (__bf16)b0.x; bf[1] = (__bf16)b0.y;
    bf[2] = (__bf16)b0.z; bf[3] = (__bf16)b0.w;
    bf[4] = (__bf16)b1.x; bf[5] = (__bf16)b1.y;
    bf[6] = (__bf16)b1.z; bf[7] = (__bf16)b1.w;
    bf16_8 a0 = *(const bf16_8*)(ap + kb);
    bf16_8 a1 = *(const bf16_8*)(ap + 16 * NK2 + kb);
    bf16_8 a2 = *(const bf16_8*)(ap + 32 * NK2 + kb);
    bf16_8 a3 = *(const bf16_8*)(ap + 48 * NK2 + kb);
    acc0 = __builtin_amdgcn_mfma_f32_16x16x32_bf16(a0, bf, acc0, 0, 0, 0);
    acc1 = __builtin_amdgcn_mfma_f32_16x16x32_bf16(a1, bf, acc1, 0, 0, 0);
    acc2 = __builtin_amdgcn_mfma_f32_16x16x32_bf16(a2, bf, acc2, 0, 0, 0);
    acc3 = __builtin_amdgcn_mfma_f32_16x16x32_bf16(a3, bf, acc3, 0, 0, 0);
  }

  if (vrow < NV) {
    float bb = bout[vrow];
    int mrow = grp * 4;  // D row = (lane>>4)*4 + reg
#pragma unroll
    for (int r = 0; r < 4; ++r) {
      out[(size_t)(mrow + r) * NV + vrow]      = acc0[r] + bb;
      out[(size_t)(16 + mrow + r) * NV + vrow] = acc1[r] + bb;
      out[(size_t)(32 + mrow + r) * NV + vrow] = acc2[r] + bb;
      out[(size_t)(48 + mrow + r) * NV + vrow] = acc3[r] + bb;
    }
  }
}

extern "C" void kernel_launch(void* const* d_in, const int* in_sizes, int n_in,
                              void* d_out, int out_size, void* d_ws, size_t ws_size,
                              hipStream_t stream) {
  const int*   x      = (const int*)d_in[0];
  const float* h      = (const float*)d_in[1];
  const float* c      = (const float*)d_in[2];
  const float* enc    = (const float*)d_in[3];
  const int*   length = (const int*)d_in[4];
  const float* emb    = (const float*)d_in[5];
  const float* Wih    = (const float*)d_in[6];
  const float* bih    = (const float*)d_in[7];
  const float* Whh    = (const float*)d_in[8];
  const float* bhh    = (const float*)d_in[9];
  const float* Wb     = (const float*)d_in[10];
  const float* Wout   = (const float*)d_in[11];
  const float* bout   = (const float*)d_in[12];

  float* out = (float*)d_out;
  float* hn  = out + (size_t)NB * NV;          // h_new region of d_out
  // c_new region = hn + NB*NH (written by k_lstm)

  float* ws      = (float*)d_ws;
  float* gates   = ws;                              // NB*4H
  float* t_ws    = gates + NB * 4 * NH;             // NB*NH
  float* energy  = t_ws + NB * NH;                  // NB*NS
  float* attn    = energy + NB * NS;                // NB*NS
  float* partial = attn + NB * NS;                  // 8*NB*NH
  float* context = partial + 8 * NB * NH;           // NB*NH
  __bf16* A_bf   = (__bf16*)(context + NB * NH);    // NB*NK2 bf16

  k_gates<<<4096 / 32, 256, 0, stream>>>(x, h, emb, Wih, bih, Whh, bhh, gates);
  k_lstm<<<NB * NH / 256, 256, 0, stream>>>(gates, c, hn);
  k_bilin<<<NB * 4, 256, 0, stream>>>(hn, Wb, t_ws);
  k_energy<<<NB * NS / 4, 256, 0, stream>>>(t_ws, enc, energy);
  k_softmax<<<NB, 256, 0, stream>>>(energy, length, attn);
  k_ctx_partial<<<NB * 4 * 8, 256, 0, stream>>>(attn, enc, partial);
  k_ctx_reduce<<<NB * NH / 256, 256, 0, stream>>>(partial, context);
  k_cvtA<<<NB * NK2 / 256, 256, 0, stream>>>(context, hn, A_bf);
  k_out_mfma<<<(NV + 63) / 64, 256, 0, stream>>>(A_bf, Wout, bout, out);
}

// Round 3
// 355.232 us; speedup vs baseline: 3.7005x; 2.0906x over previous
//
#include <hip/hip_runtime.h>
#include <math.h>

constexpr int NB = 64;
constexpr int NS = 1024;
constexpr int NH = 1024;
constexpr int NE = 1024;
constexpr int NV = 50257;
constexpr int NK2 = 2048;

typedef __bf16 bf16_8 __attribute__((ext_vector_type(8)));
typedef float  f32x4  __attribute__((ext_vector_type(4)));

// ---------------- build A_g = [emb[x] | h] (64 x 2048) in bf16
__global__ __launch_bounds__(256) void k_cvtAg(const int* __restrict__ x,
    const float* __restrict__ h, const float* __restrict__ emb,
    __bf16* __restrict__ Ag) {
  int t = blockIdx.x * 256 + threadIdx.x;  // 0..131071
  int b = t >> 11, k = t & 2047;
  float v = (k < NE) ? emb[(size_t)x[b] * NE + k] : h[b * NH + (k - NE)];
  Ag[t] = (__bf16)v;
}

// ---------------- gates GEMM via bf16 MFMA: gates[b][j] = sum_k Ag[b][k]*W[j][k] + biases
// Block = 16 columns of j; 4 waves each own a 512-wide K chunk (w0,w1->Wih; w2,w3->Whh).
// No barriers in K loop; one LDS f32x4 reduce at the end. Grid = 4096/16 = 256.
__global__ __launch_bounds__(256) void k_gates_mfma(const __bf16* __restrict__ Ag,
    const float* __restrict__ Wih, const float* __restrict__ bih,
    const float* __restrict__ Whh, const float* __restrict__ bhh,
    float* __restrict__ gates) {
  __shared__ f32x4 red[4][4][64];
  int lane = threadIdx.x & 63;
  int wave = threadIdx.x >> 6;
  int col  = lane & 15;          // j within tile (N) / A row selector (M)
  int grp  = lane >> 4;          // k-group
  int j    = blockIdx.x * 16 + col;

  const float* Wsel = (wave < 2) ? Wih : Whh;
  const float*  wp  = Wsel + (size_t)j * 1024 + (wave & 1) * 512 + grp * 8;
  const __bf16* ap  = Ag + wave * 512 + grp * 8;

  f32x4 acc[4] = {};
#pragma unroll 4
  for (int ks = 0; ks < 16; ++ks) {
    int kb = ks * 32;
    float4 b0 = *(const float4*)(wp + kb);
    float4 b1 = *(const float4*)(wp + kb + 4);
    bf16_8 bf;
    bf[0] = (__bf16)b0.x; bf[1] = (__bf16)b0.y;
    bf[2] = (__bf16)b0.z; bf[3] = (__bf16)b0.w;
    bf[4] = (__bf16)b1.x; bf[5] = (__bf16)b1.y;
    bf[6] = (__bf16)b1.z; bf[7] = (__bf16)b1.w;
#pragma unroll
    for (int m = 0; m < 4; ++m) {
      bf16_8 a = *(const bf16_8*)(ap + (m * 16 + col) * NK2 + kb);
      acc[m] = __builtin_amdgcn_mfma_f32_16x16x32_bf16(a, bf, acc[m], 0, 0, 0);
    }
  }
#pragma unroll
  for (int m = 0; m < 4; ++m) red[wave][m][lane] = acc[m];
  __syncthreads();
  // wave handles M-tile == wave
  f32x4 s = red[0][wave][lane];
#pragma unroll
  for (int wv = 1; wv < 4; ++wv) s += red[wv][wave][lane];
  float bias = bih[j] + bhh[j];
  int b = wave * 16 + grp * 4;   // C/D: row = grp*4 + r
#pragma unroll
  for (int r = 0; r < 4; ++r)
    gates[(b + r) * 4096 + j] = s[r] + bias;
}

// ---------------- LSTM cell elementwise
__global__ __launch_bounds__(256) void k_lstm(const float* __restrict__ gates,
    const float* __restrict__ c, float* __restrict__ hc_out) {
  int t = blockIdx.x * 256 + threadIdx.x;  // 0..NB*NH
  int b = t >> 10, hh = t & 1023;
  float ig = gates[b * 4096 + hh];
  float fg = gates[b * 4096 + 1024 + hh];
  float gg = gates[b * 4096 + 2048 + hh];
  float og = gates[b * 4096 + 3072 + hh];
  float i_ = 1.f / (1.f + expf(-ig));
  float f_ = 1.f / (1.f + expf(-fg));
  float g_ = tanhf(gg);
  float o_ = 1.f / (1.f + expf(-og));
  float cn = f_ * c[t] + i_ * g_;
  float hn = o_ * tanhf(cn);
  hc_out[t] = hn;                 // h_new
  hc_out[NB * NH + t] = cn;       // c_new
}

// ---------------- t = h_new @ W_bilin  (t[b][k] = sum_h hn[b][h]*Wb[h][k])
__global__ __launch_bounds__(256) void k_bilin(const float* __restrict__ hnew,
    const float* __restrict__ Wb, float* __restrict__ t_out) {
  int b = blockIdx.x >> 2;
  int k = ((blockIdx.x & 3) << 8) + threadIdx.x;
  const float* hb = hnew + b * NH;
  float acc = 0.f;
#pragma unroll 8
  for (int hh = 0; hh < NH; ++hh)
    acc += hb[hh] * Wb[hh * NH + k];
  t_out[b * NH + k] = acc;
}

// ---------------- energy[b][s] = dot(t[b], enc[b][s])   one wave per (b,s)
__global__ __launch_bounds__(256) void k_energy(const float* __restrict__ t_in,
    const float* __restrict__ enc, float* __restrict__ energy) {
  int blk = blockIdx.x;              // NB*NS/4 blocks
  int b = blk >> 8;
  int s = ((blk & 255) << 2) + (threadIdx.x >> 6);
  int lane = threadIdx.x & 63;
  const float4* tp = (const float4*)(t_in + b * NH);
  const float4* ep = (const float4*)(enc + ((size_t)b * NS + s) * NH);
  float acc = 0.f;
#pragma unroll
  for (int rep = 0; rep < 4; ++rep) {
    float4 a = tp[rep * 64 + lane];
    float4 e = ep[rep * 64 + lane];
    acc += a.x * e.x + a.y * e.y + a.z * e.z + a.w * e.w;
  }
#pragma unroll
  for (int off = 32; off; off >>= 1)
    acc += __shfl_xor(acc, off);
  if (lane == 0) energy[b * NS + s] = acc;
}

// ---------------- softmax(energy * mask) over full S (masked entries = 0, INCLUDED)
__global__ __launch_bounds__(256) void k_softmax(const float* __restrict__ energy,
    const int* __restrict__ length, float* __restrict__ attn) {
  __shared__ float red[256];
  int b = blockIdx.x, tid = threadIdx.x;
  int len = length[b];
  float vals[4];
  float m = -1e30f;
#pragma unroll
  for (int p = 0; p < 4; ++p) {
    int s = tid + p * 256;
    float v = (s < len) ? energy[b * NS + s] : 0.f;
    vals[p] = v;
    m = fmaxf(m, v);
  }
  red[tid] = m; __syncthreads();
  for (int o = 128; o; o >>= 1) { if (tid < o) red[tid] = fmaxf(red[tid], red[tid + o]); __syncthreads(); }
  m = red[0]; __syncthreads();
  float sum = 0.f;
#pragma unroll
  for (int p = 0; p < 4; ++p) { vals[p] = expf(vals[p] - m); sum += vals[p]; }
  red[tid] = sum; __syncthreads();
  for (int o = 128; o; o >>= 1) { if (tid < o) red[tid] += red[tid + o]; __syncthreads(); }
  float inv = 1.f / red[0];
#pragma unroll
  for (int p = 0; p < 4; ++p) attn[b * NS + tid + p * 256] = vals[p] * inv;
}

// ---------------- context partials over s-chunks
__global__ __launch_bounds__(256) void k_ctx_partial(const float* __restrict__ attn,
    const float* __restrict__ enc, float* __restrict__ partial) {
  int blk = blockIdx.x;      // NB*4*8
  int b = blk >> 5;
  int hc = (blk >> 3) & 3;
  int sc = blk & 7;
  int h = (hc << 8) + threadIdx.x;
  float acc = 0.f;
  int s0 = sc * 128;
  for (int s = s0; s < s0 + 128; ++s)
    acc += attn[b * NS + s] * enc[((size_t)b * NS + s) * NH + h];
  partial[((sc * NB + b) << 10) + h] = acc;
}

__global__ __launch_bounds__(256) void k_ctx_reduce(const float* __restrict__ partial,
    float* __restrict__ context) {
  int t = blockIdx.x * 256 + threadIdx.x;  // NB*NH
  float acc = 0.f;
#pragma unroll
  for (int sc = 0; sc < 8; ++sc) acc += partial[((sc * NB) << 10) + t];
  context[t] = acc;
}

// ---------------- convert A = [context | h_new] (64 x 2048) to bf16
__global__ __launch_bounds__(256) void k_cvtA(const float* __restrict__ ctx,
    const float* __restrict__ hn, __bf16* __restrict__ A) {
  int t = blockIdx.x * 256 + threadIdx.x;  // 0..131071
  int b = t >> 11, k = t & 2047;
  float v = (k < NH) ? ctx[b * NH + k] : hn[b * NH + (k - NH)];
  A[t] = (__bf16)v;
}

// ---------------- out[b][v] = dot(A[b], W_out[v]) + b_out[v]  via bf16 MFMA
__global__ __launch_bounds__(256) void k_out_mfma(const __bf16* __restrict__ A,
    const float* __restrict__ Wout, const float* __restrict__ bout,
    float* __restrict__ out) {
  int lane = threadIdx.x & 63;
  int wave = threadIdx.x >> 6;
  int col  = lane & 15;          // N index within tile / M-row index for A frags
  int grp  = lane >> 4;          // 0..3 (k-group)
  int v0   = blockIdx.x * 64 + wave * 16;
  int vrow = v0 + col;
  int vcl  = vrow < NV ? vrow : NV - 1;

  const float*  wp = Wout + (size_t)vcl * NK2 + grp * 8;
  const __bf16* ap = A + col * NK2 + grp * 8;

  f32x4 acc0 = {0.f, 0.f, 0.f, 0.f};
  f32x4 acc1 = {0.f, 0.f, 0.f, 0.f};
  f32x4 acc2 = {0.f, 0.f, 0.f, 0.f};
  f32x4 acc3 = {0.f, 0.f, 0.f, 0.f};

#pragma unroll 4
  for (int ks = 0; ks < 64; ++ks) {
    int kb = ks * 32;
    float4 b0 = *(const float4*)(wp + kb);
    float4 b1 = *(const float4*)(wp + kb + 4);
    bf16_8 bf;
    bf[0] = (__bf16)b0.x; bf[1] = (__bf16)b0.y;
    bf[2] = (__bf16)b0.z; bf[3] = (__bf16)b0.w;
    bf[4] = (__bf16)b1.x; bf[5] = (__bf16)b1.y;
    bf[6] = (__bf16)b1.z; bf[7] = (__bf16)b1.w;
    bf16_8 a0 = *(const bf16_8*)(ap + kb);
    bf16_8 a1 = *(const bf16_8*)(ap + 16 * NK2 + kb);
    bf16_8 a2 = *(const bf16_8*)(ap + 32 * NK2 + kb);
    bf16_8 a3 = *(const bf16_8*)(ap + 48 * NK2 + kb);
    acc0 = __builtin_amdgcn_mfma_f32_16x16x32_bf16(a0, bf, acc0, 0, 0, 0);
    acc1 = __builtin_amdgcn_mfma_f32_16x16x32_bf16(a1, bf, acc1, 0, 0, 0);
    acc2 = __builtin_amdgcn_mfma_f32_16x16x32_bf16(a2, bf, acc2, 0, 0, 0);
    acc3 = __builtin_amdgcn_mfma_f32_16x16x32_bf16(a3, bf, acc3, 0, 0, 0);
  }

  if (vrow < NV) {
    float bb = bout[vrow];
    int mrow = grp * 4;  // D row = (lane>>4)*4 + reg
#pragma unroll
    for (int r = 0; r < 4; ++r) {
      out[(size_t)(mrow + r) * NV + vrow]      = acc0[r] + bb;
      out[(size_t)(16 + mrow + r) * NV + vrow] = acc1[r] + bb;
      out[(size_t)(32 + mrow + r) * NV + vrow] = acc2[r] + bb;
      out[(size_t)(48 + mrow + r) * NV + vrow] = acc3[r] + bb;
    }
  }
}

extern "C" void kernel_launch(void* const* d_in, const int* in_sizes, int n_in,
                              void* d_out, int out_size, void* d_ws, size_t ws_size,
                              hipStream_t stream) {
  const int*   x      = (const int*)d_in[0];
  const float* h      = (const float*)d_in[1];
  const float* c      = (const float*)d_in[2];
  const float* enc    = (const float*)d_in[3];
  const int*   length = (const int*)d_in[4];
  const float* emb    = (const float*)d_in[5];
  const float* Wih    = (const float*)d_in[6];
  const float* bih    = (const float*)d_in[7];
  const float* Whh    = (const float*)d_in[8];
  const float* bhh    = (const float*)d_in[9];
  const float* Wb     = (const float*)d_in[10];
  const float* Wout   = (const float*)d_in[11];
  const float* bout   = (const float*)d_in[12];

  float* out = (float*)d_out;
  float* hn  = out + (size_t)NB * NV;          // h_new region of d_out
  // c_new region = hn + NB*NH (written by k_lstm)

  float* ws      = (float*)d_ws;
  float* gates   = ws;                              // NB*4H
  float* t_ws    = gates + NB * 4 * NH;             // NB*NH
  float* energy  = t_ws + NB * NH;                  // NB*NS
  float* attn    = energy + NB * NS;                // NB*NS
  float* partial = attn + NB * NS;                  // 8*NB*NH
  float* context = partial + 8 * NB * NH;           // NB*NH
  __bf16* A_bf   = (__bf16*)(context + NB * NH);    // NB*NK2 bf16
  __bf16* Ag_bf  = A_bf + NB * NK2;                 // NB*NK2 bf16

  k_cvtAg<<<NB * NK2 / 256, 256, 0, stream>>>(x, h, emb, Ag_bf);
  k_gates_mfma<<<4096 / 16, 256, 0, stream>>>(Ag_bf, Wih, bih, Whh, bhh, gates);
  k_lstm<<<NB * NH / 256, 256, 0, stream>>>(gates, c, hn);
  k_bilin<<<NB * 4, 256, 0, stream>>>(hn, Wb, t_ws);
  k_energy<<<NB * NS / 4, 256, 0, stream>>>(t_ws, enc, energy);
  k_softmax<<<NB, 256, 0, stream>>>(energy, length, attn);
  k_ctx_partial<<<NB * 4 * 8, 256, 0, stream>>>(attn, enc, partial);
  k_ctx_reduce<<<NB * NH / 256, 256, 0, stream>>>(partial, context);
  k_cvtA<<<NB * NK2 / 256, 256, 0, stream>>>(context, hn, A_bf);
  k_out_mfma<<<(NV + 63) / 64, 256, 0, stream>>>(A_bf, Wout, bout, out);
}